// Round 1
// baseline (8688.370 us; speedup 1.0000x reference)
//
#include <hip/hip_runtime.h>
#include <math.h>

#define D_MODEL 1024
#define NUM_HEADS 16
#define DK 64
#define L_SEQ 2048
#define BATCH 2
#define LN_EPS 1e-5f
#define ENERGY_SCALE 0.1f
#define TL 4   // query rows per attention block

__device__ __forceinline__ float waveReduceSum(float v) {
#pragma unroll
    for (int off = 32; off > 0; off >>= 1) v += __shfl_xor(v, off, 64);
    return v;
}
__device__ __forceinline__ float waveReduceMax(float v) {
#pragma unroll
    for (int off = 32; off > 0; off >>= 1) v = fmaxf(v, __shfl_xor(v, off, 64));
    return v;
}

// C[M,N] = A[M,K] * B[N,K]^T (+bias[n]); 128x128 tile, K-step 16, 256 threads.
// LDS stored k-major (As[kk][row]) so inner loop uses float4 LDS reads.
__global__ __launch_bounds__(256) void gemm_nt(
    const float* __restrict__ A, const float* __restrict__ B,
    const float* __restrict__ bias, float* __restrict__ C,
    int N, int K, long long sA, long long sB, long long sC)
{
    A += (long long)blockIdx.z * sA;
    B += (long long)blockIdx.z * sB;
    C += (long long)blockIdx.z * sC;
    __shared__ float As[16][132];
    __shared__ float Bs[16][132];
    const int tid = threadIdx.x;
    const int tx = tid & 15, ty = tid >> 4;
    const int row0 = blockIdx.y * 128, col0 = blockIdx.x * 128;
    float acc[8][8] = {};
    for (int k0 = 0; k0 < K; k0 += 16) {
#pragma unroll
        for (int p = 0; p < 2; p++) {
            int q = tid + p * 256;        // float4 id 0..511
            int r = q >> 2;               // 0..127
            int kq = (q & 3) << 2;        // 0,4,8,12
            float4 av = *(const float4*)(A + (long long)(row0 + r) * K + k0 + kq);
            float4 bv = *(const float4*)(B + (long long)(col0 + r) * K + k0 + kq);
            As[kq + 0][r] = av.x; As[kq + 1][r] = av.y; As[kq + 2][r] = av.z; As[kq + 3][r] = av.w;
            Bs[kq + 0][r] = bv.x; Bs[kq + 1][r] = bv.y; Bs[kq + 2][r] = bv.z; Bs[kq + 3][r] = bv.w;
        }
        __syncthreads();
#pragma unroll
        for (int kk = 0; kk < 16; kk++) {
            float4 a0 = *(const float4*)&As[kk][ty * 8];
            float4 a1 = *(const float4*)&As[kk][ty * 8 + 4];
            float4 b0 = *(const float4*)&Bs[kk][tx * 8];
            float4 b1 = *(const float4*)&Bs[kk][tx * 8 + 4];
            float a[8] = {a0.x, a0.y, a0.z, a0.w, a1.x, a1.y, a1.z, a1.w};
            float bb[8] = {b0.x, b0.y, b0.z, b0.w, b1.x, b1.y, b1.z, b1.w};
#pragma unroll
            for (int i = 0; i < 8; i++)
#pragma unroll
                for (int j = 0; j < 8; j++)
                    acc[i][j] = fmaf(a[i], bb[j], acc[i][j]);
        }
        __syncthreads();
    }
#pragma unroll
    for (int i = 0; i < 8; i++) {
        long long r = row0 + ty * 8 + i;
#pragma unroll
        for (int j = 0; j < 8; j += 4) {
            int c = col0 + tx * 8 + j;
            float4 v = {acc[i][j], acc[i][j + 1], acc[i][j + 2], acc[i][j + 3]};
            if (bias) { v.x += bias[c]; v.y += bias[c + 1]; v.z += bias[c + 2]; v.w += bias[c + 3]; }
            *(float4*)(C + r * N + c) = v;
        }
    }
}

// Row LayerNorm over D_MODEL=1024, optional residual add. One block per row.
__global__ __launch_bounds__(256) void ln_rows(
    const float* __restrict__ in, const float* __restrict__ res,
    const float* __restrict__ g, const float* __restrict__ bta,
    float* __restrict__ out)
{
    const long long row = blockIdx.x;
    const float* ip = in + row * D_MODEL;
    const float* rp = res ? res + row * D_MODEL : nullptr;
    const int tid = threadIdx.x;
    float vals[4];
    float s = 0.f, ss = 0.f;
#pragma unroll
    for (int j = 0; j < 4; j++) {
        int idx = tid + j * 256;
        float v = ip[idx];
        if (rp) v += rp[idx];
        vals[j] = v; s += v; ss += v * v;
    }
    __shared__ float sred[4], ssred[4];
    s = waveReduceSum(s); ss = waveReduceSum(ss);
    int wave = tid >> 6, lane = tid & 63;
    if (lane == 0) { sred[wave] = s; ssred[wave] = ss; }
    __syncthreads();
    float ts = sred[0] + sred[1] + sred[2] + sred[3];
    float tss = ssred[0] + ssred[1] + ssred[2] + ssred[3];
    float mu = ts * (1.f / D_MODEL);
    float var = tss * (1.f / D_MODEL) - mu * mu;
    float rs = rsqrtf(var + LN_EPS);
    float* op = out + row * D_MODEL;
#pragma unroll
    for (int j = 0; j < 4; j++) {
        int idx = tid + j * 256;
        op[idx] = (vals[j] - mu) * rs * g[idx] + bta[idx];
    }
}

// Fused: scores = QK^T/8 + 0.1*EB  -> softmax -> write attn -> ctx = attn*V
// One block handles TL=4 query rows for one (b,h). 256 threads.
__global__ __launch_bounds__(256) void attn_fused(
    const float* __restrict__ Qm, const float* __restrict__ Km,
    const float* __restrict__ Vm, const float* __restrict__ EB,
    float* __restrict__ attn_out, float* __restrict__ CTX)
{
    const int l0 = blockIdx.x * TL;
    const int h = blockIdx.y, b = blockIdx.z;
    const int tid = threadIdx.x;
    __shared__ float qs[TL][DK];
    __shared__ float arow[TL][L_SEQ];        // 32 KB, unnormalized exp values
    __shared__ float redmax[TL][4];
    __shared__ float redsum[TL][4];
    __shared__ float redv[4][TL][DK];

    {
        int r = tid >> 6, d = tid & 63;
        qs[r][d] = Qm[((long long)b * L_SEQ + l0 + r) * D_MODEL + h * DK + d];
    }
    __syncthreads();

    const float* ebbase = EB + ((long long)b * L_SEQ + l0) * L_SEQ;
    float sc[TL][8];
    float lmax[TL] = {-1e30f, -1e30f, -1e30f, -1e30f};

#pragma unroll
    for (int j = 0; j < 8; j += 2) {
        int ma = tid + j * 256;
        int mb = ma + 256;
        const float4* kpa = (const float4*)(Km + ((long long)b * L_SEQ + ma) * D_MODEL + h * DK);
        const float4* kpb = (const float4*)(Km + ((long long)b * L_SEQ + mb) * D_MODEL + h * DK);
        float da[TL] = {0.f, 0.f, 0.f, 0.f};
        float db[TL] = {0.f, 0.f, 0.f, 0.f};
#pragma unroll
        for (int i = 0; i < 16; i++) {
            float4 ka = kpa[i];
            float4 kb = kpb[i];
#pragma unroll
            for (int r = 0; r < TL; r++) {
                float4 qv = ((const float4*)&qs[r][0])[i];
                da[r] = fmaf(qv.x, ka.x, da[r]); da[r] = fmaf(qv.y, ka.y, da[r]);
                da[r] = fmaf(qv.z, ka.z, da[r]); da[r] = fmaf(qv.w, ka.w, da[r]);
                db[r] = fmaf(qv.x, kb.x, db[r]); db[r] = fmaf(qv.y, kb.y, db[r]);
                db[r] = fmaf(qv.z, kb.z, db[r]); db[r] = fmaf(qv.w, kb.w, db[r]);
            }
        }
#pragma unroll
        for (int r = 0; r < TL; r++) {
            float sa = da[r] * 0.125f + ENERGY_SCALE * ebbase[(long long)r * L_SEQ + ma];
            float sb = db[r] * 0.125f + ENERGY_SCALE * ebbase[(long long)r * L_SEQ + mb];
            sc[r][j] = sa; sc[r][j + 1] = sb;
            lmax[r] = fmaxf(lmax[r], fmaxf(sa, sb));
        }
    }

    const int wave = tid >> 6, lane = tid & 63;
#pragma unroll
    for (int r = 0; r < TL; r++) {
        float w = waveReduceMax(lmax[r]);
        if (lane == 0) redmax[r][wave] = w;
    }
    __syncthreads();
    float bmax[TL];
#pragma unroll
    for (int r = 0; r < TL; r++)
        bmax[r] = fmaxf(fmaxf(redmax[r][0], redmax[r][1]), fmaxf(redmax[r][2], redmax[r][3]));

    float lsum[TL] = {0.f, 0.f, 0.f, 0.f};
#pragma unroll
    for (int r = 0; r < TL; r++) {
#pragma unroll
        for (int j = 0; j < 8; j++) {
            float e = __expf(sc[r][j] - bmax[r]);
            sc[r][j] = e;
            lsum[r] += e;
            arow[r][tid + j * 256] = e;
        }
    }
#pragma unroll
    for (int r = 0; r < TL; r++) {
        float w = waveReduceSum(lsum[r]);
        if (lane == 0) redsum[r][wave] = w;
    }
    __syncthreads();

    float inv[TL];
#pragma unroll
    for (int r = 0; r < TL; r++)
        inv[r] = 1.f / (redsum[r][0] + redsum[r][1] + redsum[r][2] + redsum[r][3]);

    // write normalized attention rows (coalesced)
#pragma unroll
    for (int r = 0; r < TL; r++) {
        float* ao = attn_out + (((long long)(b * NUM_HEADS + h)) * L_SEQ + l0 + r) * L_SEQ;
#pragma unroll
        for (int j = 0; j < 8; j++)
            ao[tid + j * 256] = sc[r][j] * inv[r];
    }

    // ctx phase: thread (d, chunk) accumulates 512 m's for 4 rows
    const int d = tid & 63, chunk = tid >> 6;
    const float* vp = Vm + ((long long)b * L_SEQ + chunk * 512) * D_MODEL + h * DK + d;
    float acc[TL] = {0.f, 0.f, 0.f, 0.f};
    for (int m = 0; m < 512; m++) {
        float vv = vp[(long long)m * D_MODEL];
#pragma unroll
        for (int r = 0; r < TL; r++)
            acc[r] = fmaf(arow[r][chunk * 512 + m], vv, acc[r]);
    }
#pragma unroll
    for (int r = 0; r < TL; r++) redv[chunk][r][d] = acc[r];
    __syncthreads();
    {
        int r = tid >> 6, dd = tid & 63;
        float invr = 1.f / (redsum[r][0] + redsum[r][1] + redsum[r][2] + redsum[r][3]);
        float s = redv[0][r][dd] + redv[1][r][dd] + redv[2][r][dd] + redv[3][r][dd];
        CTX[((long long)b * L_SEQ + l0 + r) * D_MODEL + h * DK + dd] = s * invr;
    }
}

extern "C" void kernel_launch(void* const* d_in, const int* in_sizes, int n_in,
                              void* d_out, int out_size, void* d_ws, size_t ws_size,
                              hipStream_t stream) {
    const float* x    = (const float*)d_in[0];
    const float* wq   = (const float*)d_in[1];
    const float* wk   = (const float*)d_in[2];
    const float* wv   = (const float*)d_in[3];
    const float* wo_w = (const float*)d_in[4];
    const float* wo_b = (const float*)d_in[5];
    const float* ep_w = (const float*)d_in[6];
    const float* ep_b = (const float*)d_in[7];
    const float* en_g = (const float*)d_in[8];
    const float* en_b = (const float*)d_in[9];
    const float* ln_g = (const float*)d_in[10];
    const float* ln_b = (const float*)d_in[11];

    float* out_final = (float*)d_out;
    float* attn_out  = out_final + (long long)BATCH * L_SEQ * D_MODEL;

    const long long MD = (long long)BATCH * L_SEQ * D_MODEL;   // 4,194,304
    float* ws  = (float*)d_ws;
    float* Q   = ws;
    float* K   = Q + MD;
    float* V   = K + MD;
    float* EF  = V + MD;
    float* EB  = EF + MD;                 // 2*2048*2048 = 8,388,608 floats
    float* CTX = EB + (long long)BATCH * L_SEQ * L_SEQ;
    float* OUT = Q;                       // reuse Q (dead after attn_fused)

    const int M = BATCH * L_SEQ;          // 4096
    dim3 blk(256);
    dim3 gp(D_MODEL / 128, M / 128, 1);   // projections: (8, 32)

    gemm_nt<<<gp, blk, 0, stream>>>(x, wq, nullptr, Q, D_MODEL, D_MODEL, 0, 0, 0);
    gemm_nt<<<gp, blk, 0, stream>>>(x, wk, nullptr, K, D_MODEL, D_MODEL, 0, 0, 0);
    gemm_nt<<<gp, blk, 0, stream>>>(x, wv, nullptr, V, D_MODEL, D_MODEL, 0, 0, 0);
    gemm_nt<<<gp, blk, 0, stream>>>(x, ep_w, ep_b, EF, D_MODEL, D_MODEL, 0, 0, 0);

    ln_rows<<<dim3(M), blk, 0, stream>>>(EF, nullptr, en_g, en_b, EF);

    dim3 ge(L_SEQ / 128, L_SEQ / 128, BATCH);   // (16,16,2)
    gemm_nt<<<ge, blk, 0, stream>>>(EF, EF, nullptr, EB, L_SEQ, D_MODEL,
                                    (long long)L_SEQ * D_MODEL,
                                    (long long)L_SEQ * D_MODEL,
                                    (long long)L_SEQ * L_SEQ);

    dim3 ga(L_SEQ / TL, NUM_HEADS, BATCH);      // (512,16,2)
    attn_fused<<<ga, blk, 0, stream>>>(Q, K, V, EB, attn_out, CTX);

    gemm_nt<<<gp, blk, 0, stream>>>(CTX, wo_w, wo_b, OUT, D_MODEL, D_MODEL, 0, 0, 0);

    ln_rows<<<dim3(M), blk, 0, stream>>>(OUT, x, ln_g, ln_b, out_final);
}

// Round 2
// 1772.163 us; speedup vs baseline: 4.9027x; 4.9027x over previous
//
#include <hip/hip_runtime.h>
#include <math.h>

#define D_MODEL 1024
#define NUM_HEADS 16
#define DK 64
#define L_SEQ 2048
#define BATCH 2
#define LN_EPS 1e-5f
#define ENERGY_SCALE 0.1f

typedef __attribute__((ext_vector_type(8))) short short8;
typedef __attribute__((ext_vector_type(4))) float f32x4;

__device__ __forceinline__ float waveReduceSum(float v) {
#pragma unroll
    for (int off = 32; off > 0; off >>= 1) v += __shfl_xor(v, off, 64);
    return v;
}

__device__ __forceinline__ unsigned short f2bf(float f) {
    unsigned int u = __float_as_uint(f);
    u += 0x7fff + ((u >> 16) & 1);          // round-to-nearest-even
    return (unsigned short)(u >> 16);
}

// ---------------- fp32 tiled GEMM (unchanged from baseline) ----------------
__global__ __launch_bounds__(256) void gemm_nt(
    const float* __restrict__ A, const float* __restrict__ B,
    const float* __restrict__ bias, float* __restrict__ C,
    int N, int K, long long sA, long long sB, long long sC)
{
    A += (long long)blockIdx.z * sA;
    B += (long long)blockIdx.z * sB;
    C += (long long)blockIdx.z * sC;
    __shared__ float As[16][132];
    __shared__ float Bs[16][132];
    const int tid = threadIdx.x;
    const int tx = tid & 15, ty = tid >> 4;
    const int row0 = blockIdx.y * 128, col0 = blockIdx.x * 128;
    float acc[8][8] = {};
    for (int k0 = 0; k0 < K; k0 += 16) {
#pragma unroll
        for (int p = 0; p < 2; p++) {
            int q = tid + p * 256;
            int r = q >> 2;
            int kq = (q & 3) << 2;
            float4 av = *(const float4*)(A + (long long)(row0 + r) * K + k0 + kq);
            float4 bv = *(const float4*)(B + (long long)(col0 + r) * K + k0 + kq);
            As[kq + 0][r] = av.x; As[kq + 1][r] = av.y; As[kq + 2][r] = av.z; As[kq + 3][r] = av.w;
            Bs[kq + 0][r] = bv.x; Bs[kq + 1][r] = bv.y; Bs[kq + 2][r] = bv.z; Bs[kq + 3][r] = bv.w;
        }
        __syncthreads();
#pragma unroll
        for (int kk = 0; kk < 16; kk++) {
            float4 a0 = *(const float4*)&As[kk][ty * 8];
            float4 a1 = *(const float4*)&As[kk][ty * 8 + 4];
            float4 b0 = *(const float4*)&Bs[kk][tx * 8];
            float4 b1 = *(const float4*)&Bs[kk][tx * 8 + 4];
            float a[8] = {a0.x, a0.y, a0.z, a0.w, a1.x, a1.y, a1.z, a1.w};
            float bb[8] = {b0.x, b0.y, b0.z, b0.w, b1.x, b1.y, b1.z, b1.w};
#pragma unroll
            for (int i = 0; i < 8; i++)
#pragma unroll
                for (int j = 0; j < 8; j++)
                    acc[i][j] = fmaf(a[i], bb[j], acc[i][j]);
        }
        __syncthreads();
    }
#pragma unroll
    for (int i = 0; i < 8; i++) {
        long long r = row0 + ty * 8 + i;
#pragma unroll
        for (int j = 0; j < 8; j += 4) {
            int c = col0 + tx * 8 + j;
            float4 v = {acc[i][j], acc[i][j + 1], acc[i][j + 2], acc[i][j + 3]};
            if (bias) { v.x += bias[c]; v.y += bias[c + 1]; v.z += bias[c + 2]; v.w += bias[c + 3]; }
            *(float4*)(C + r * N + c) = v;
        }
    }
}

// ---------------- LayerNorm rows (unchanged) ----------------
__global__ __launch_bounds__(256) void ln_rows(
    const float* __restrict__ in, const float* __restrict__ res,
    const float* __restrict__ g, const float* __restrict__ bta,
    float* __restrict__ out)
{
    const long long row = blockIdx.x;
    const float* ip = in + row * D_MODEL;
    const float* rp = res ? res + row * D_MODEL : nullptr;
    const int tid = threadIdx.x;
    float vals[4];
    float s = 0.f, ss = 0.f;
#pragma unroll
    for (int j = 0; j < 4; j++) {
        int idx = tid + j * 256;
        float v = ip[idx];
        if (rp) v += rp[idx];
        vals[j] = v; s += v; ss += v * v;
    }
    __shared__ float sred[4], ssred[4];
    s = waveReduceSum(s); ss = waveReduceSum(ss);
    int wave = tid >> 6, lane = tid & 63;
    if (lane == 0) { sred[wave] = s; ssred[wave] = ss; }
    __syncthreads();
    float ts = sred[0] + sred[1] + sred[2] + sred[3];
    float tss = ssred[0] + ssred[1] + ssred[2] + ssred[3];
    float mu = ts * (1.f / D_MODEL);
    float var = tss * (1.f / D_MODEL) - mu * mu;
    float rs = rsqrtf(var + LN_EPS);
    float* op = out + row * D_MODEL;
#pragma unroll
    for (int j = 0; j < 4; j++) {
        int idx = tid + j * 256;
        op[idx] = (vals[j] - mu) * rs * g[idx] + bta[idx];
    }
}

// ---------------- fp32 -> bf16 convert (two matrices via blockIdx.y) ----------------
__global__ __launch_bounds__(256) void cvt_bf16(
    const float* __restrict__ a, const float* __restrict__ b,
    unsigned short* __restrict__ ah, unsigned short* __restrict__ bh)
{
    const float* src = blockIdx.y ? b : a;
    unsigned short* dst = blockIdx.y ? bh : ah;
    long long i = ((long long)blockIdx.x * 256 + threadIdx.x) * 4;
    float4 v = *(const float4*)(src + i);
    ushort4 o;
    o.x = f2bf(v.x); o.y = f2bf(v.y); o.z = f2bf(v.z); o.w = f2bf(v.w);
    *(ushort4*)(dst + i) = o;
}

// ---------------- V transpose: V[B,L,D] fp32 -> Vt[B,H,DK,L] bf16 ----------------
__global__ __launch_bounds__(256) void transpose_v(
    const float* __restrict__ V, unsigned short* __restrict__ Vt)
{
    const int m0 = blockIdx.x * 64, h = blockIdx.y, b = blockIdx.z;
    __shared__ float t[64][65];
    const int tid = threadIdx.x;
    {
        int r = tid >> 4, c4 = (tid & 15) * 4;
#pragma unroll
        for (int i = 0; i < 4; i++) {
            int row = r + i * 16;
            float4 v = *(const float4*)(V + ((long long)b * L_SEQ + m0 + row) * D_MODEL + h * DK + c4);
            t[row][c4] = v.x; t[row][c4 + 1] = v.y; t[row][c4 + 2] = v.z; t[row][c4 + 3] = v.w;
        }
    }
    __syncthreads();
    const int lane = tid & 63, wv = tid >> 6;
#pragma unroll
    for (int i = 0; i < 16; i++) {
        int d = wv * 16 + i;
        Vt[(((long long)(b * NUM_HEADS + h)) * DK + d) * L_SEQ + m0 + lane] = f2bf(t[lane][d]);
    }
}

// ---------------- MFMA attention ----------------
// Block: 256 thr (4 waves), 64 query rows for one (b,h). Two sweeps over m:
// sweep 1: S = Q K^T/8 + 0.1 EB via mfma, online row max/sum (registers only)
// sweep 2: recompute S, p = exp(s-M)/sum -> attn_out; P (bf16 via LDS) @ V via mfma -> ctx
__global__ __launch_bounds__(256) void attn_mfma(
    const unsigned short* __restrict__ Qh, const unsigned short* __restrict__ Kh,
    const unsigned short* __restrict__ Vt, const float* __restrict__ EB,
    float* __restrict__ attn_out, float* __restrict__ CTX)
{
    __shared__ unsigned short Qs[64 * 72];
    __shared__ unsigned short Ks[64 * 72];
    __shared__ unsigned short Vts[64 * 72];
    __shared__ unsigned short Ps[4 * 16 * 72];

    const int tid = threadIdx.x;
    const int lane = tid & 63, w = tid >> 6;
    const int quad = lane >> 4, col = lane & 15;
    const int l0 = blockIdx.x * 64;
    const int h = blockIdx.y, b = blockIdx.z;

    // ---- stage Q tile (persistent) ----
    {
        const unsigned short* g = Qh + ((long long)b * L_SEQ + l0) * D_MODEL + h * DK;
        int r = tid >> 2, c0 = (tid & 3) * 16;
#pragma unroll
        for (int i = 0; i < 2; i++) {
            int c = c0 + i * 8;
            *(uint4*)(Qs + r * 72 + c) = *(const uint4*)(g + (long long)r * D_MODEL + c);
        }
    }
    __syncthreads();

    short8 aq[2];
    {
        int arow = w * 16 + col;
#pragma unroll
        for (int kc = 0; kc < 2; kc++)
            aq[kc] = *(const short8*)(Qs + arow * 72 + quad * 8 + kc * 32);
    }

    const float* ebp = EB + ((long long)b * L_SEQ + l0 + w * 16 + quad * 4) * L_SEQ + col;
    const unsigned short* kbase = Kh + ((long long)b * L_SEQ) * D_MODEL + h * DK;
    const unsigned short* vbase = Vt + ((long long)(b * NUM_HEADS + h)) * DK * L_SEQ;

    float rowM[4] = {-1e30f, -1e30f, -1e30f, -1e30f};
    float rowS[4] = {0.f, 0.f, 0.f, 0.f};

    // ================= sweep 1: row max & sum =================
    for (int m0 = 0; m0 < L_SEQ; m0 += 64) {
        __syncthreads();
        {   // stage K tile
            int r = tid >> 2, c0 = (tid & 3) * 16;
#pragma unroll
            for (int i = 0; i < 2; i++) {
                int c = c0 + i * 8;
                *(uint4*)(Ks + r * 72 + c) = *(const uint4*)(kbase + (long long)(m0 + r) * D_MODEL + c);
            }
        }
        __syncthreads();

        f32x4 acc[4];
#pragma unroll
        for (int nt = 0; nt < 4; nt++) acc[nt] = (f32x4){0.f, 0.f, 0.f, 0.f};
#pragma unroll
        for (int nt = 0; nt < 4; nt++)
#pragma unroll
            for (int kc = 0; kc < 2; kc++) {
                short8 bk = *(const short8*)(Ks + (nt * 16 + col) * 72 + quad * 8 + kc * 32);
                acc[nt] = __builtin_amdgcn_mfma_f32_16x16x32_bf16(aq[kc], bk, acc[nt], 0, 0, 0);
            }

        float sv[4][4];
#pragma unroll
        for (int nt = 0; nt < 4; nt++)
#pragma unroll
            for (int reg = 0; reg < 4; reg++)
                sv[nt][reg] = acc[nt][reg] * 0.125f +
                              ENERGY_SCALE * ebp[(long long)reg * L_SEQ + m0 + nt * 16];

#pragma unroll
        for (int reg = 0; reg < 4; reg++) {
            float tm = fmaxf(fmaxf(sv[0][reg], sv[1][reg]), fmaxf(sv[2][reg], sv[3][reg]));
#pragma unroll
            for (int off = 8; off > 0; off >>= 1) tm = fmaxf(tm, __shfl_xor(tm, off, 64));
            float nm = fmaxf(rowM[reg], tm);
            float t = __expf(sv[0][reg] - nm) + __expf(sv[1][reg] - nm) +
                      __expf(sv[2][reg] - nm) + __expf(sv[3][reg] - nm);
#pragma unroll
            for (int off = 8; off > 0; off >>= 1) t += __shfl_xor(t, off, 64);
            rowS[reg] = rowS[reg] * __expf(rowM[reg] - nm) + t;
            rowM[reg] = nm;
        }
    }

    float invS[4];
#pragma unroll
    for (int reg = 0; reg < 4; reg++) invS[reg] = 1.f / rowS[reg];

    // ================= sweep 2: write attn, ctx = P V =================
    f32x4 ctx[4];
#pragma unroll
    for (int nt = 0; nt < 4; nt++) ctx[nt] = (f32x4){0.f, 0.f, 0.f, 0.f};

    unsigned short* Psw = Ps + w * 16 * 72;
    float* aob = attn_out + (((long long)(b * NUM_HEADS + h)) * L_SEQ + l0 + w * 16 + quad * 4) * L_SEQ + col;

    for (int m0 = 0; m0 < L_SEQ; m0 += 64) {
        __syncthreads();
        {   // stage K tile + V^T tile
            int r = tid >> 2, c0 = (tid & 3) * 16;
#pragma unroll
            for (int i = 0; i < 2; i++) {
                int c = c0 + i * 8;
                *(uint4*)(Ks + r * 72 + c) = *(const uint4*)(kbase + (long long)(m0 + r) * D_MODEL + c);
                *(uint4*)(Vts + r * 72 + c) = *(const uint4*)(vbase + (long long)r * L_SEQ + m0 + c);
            }
        }
        __syncthreads();

        f32x4 acc[4];
#pragma unroll
        for (int nt = 0; nt < 4; nt++) acc[nt] = (f32x4){0.f, 0.f, 0.f, 0.f};
#pragma unroll
        for (int nt = 0; nt < 4; nt++)
#pragma unroll
            for (int kc = 0; kc < 2; kc++) {
                short8 bk = *(const short8*)(Ks + (nt * 16 + col) * 72 + quad * 8 + kc * 32);
                acc[nt] = __builtin_amdgcn_mfma_f32_16x16x32_bf16(aq[kc], bk, acc[nt], 0, 0, 0);
            }

#pragma unroll
        for (int nt = 0; nt < 4; nt++)
#pragma unroll
            for (int reg = 0; reg < 4; reg++) {
                float s = acc[nt][reg] * 0.125f +
                          ENERGY_SCALE * ebp[(long long)reg * L_SEQ + m0 + nt * 16];
                float p = __expf(s - rowM[reg]) * invS[reg];
                aob[(long long)reg * L_SEQ + m0 + nt * 16] = p;
                Psw[(quad * 4 + reg) * 72 + nt * 16 + col] = f2bf(p);
            }

        short8 ap[2];
#pragma unroll
        for (int kc = 0; kc < 2; kc++)
            ap[kc] = *(const short8*)(Psw + col * 72 + quad * 8 + kc * 32);
#pragma unroll
        for (int nt = 0; nt < 4; nt++)
#pragma unroll
            for (int kc = 0; kc < 2; kc++) {
                short8 bv = *(const short8*)(Vts + (nt * 16 + col) * 72 + quad * 8 + kc * 32);
                ctx[nt] = __builtin_amdgcn_mfma_f32_16x16x32_bf16(ap[kc], bv, ctx[nt], 0, 0, 0);
            }
    }

    // epilogue: ctx -> CTX[B,L,D]
#pragma unroll
    for (int nt = 0; nt < 4; nt++)
#pragma unroll
        for (int reg = 0; reg < 4; reg++)
            CTX[((long long)b * L_SEQ + l0 + w * 16 + quad * 4 + reg) * D_MODEL + h * DK + nt * 16 + col] = ctx[nt][reg];
}

extern "C" void kernel_launch(void* const* d_in, const int* in_sizes, int n_in,
                              void* d_out, int out_size, void* d_ws, size_t ws_size,
                              hipStream_t stream) {
    const float* x    = (const float*)d_in[0];
    const float* wq   = (const float*)d_in[1];
    const float* wk   = (const float*)d_in[2];
    const float* wv   = (const float*)d_in[3];
    const float* wo_w = (const float*)d_in[4];
    const float* wo_b = (const float*)d_in[5];
    const float* ep_w = (const float*)d_in[6];
    const float* ep_b = (const float*)d_in[7];
    const float* en_g = (const float*)d_in[8];
    const float* en_b = (const float*)d_in[9];
    const float* ln_g = (const float*)d_in[10];
    const float* ln_b = (const float*)d_in[11];

    float* out_final = (float*)d_out;
    float* attn_out  = out_final + (long long)BATCH * L_SEQ * D_MODEL;

    const long long MD = (long long)BATCH * L_SEQ * D_MODEL;   // 4,194,304
    float* ws  = (float*)d_ws;
    float* Q   = ws;
    float* K   = Q + MD;
    float* V   = K + MD;
    float* EF  = V + MD;
    float* EB  = EF + MD;                                      // [B,L,L] = 2*MD floats
    float* CTX = EB + (long long)BATCH * L_SEQ * L_SEQ;
    unsigned short* Qh = (unsigned short*)(CTX + MD);
    unsigned short* Kh = Qh + MD;
    unsigned short* Vt = Kh + MD;
    float* OUT = Q;                                            // Q fp32 dead after cvt

    const int M = BATCH * L_SEQ;                               // 4096
    dim3 blk(256);
    dim3 gp(D_MODEL / 128, M / 128, 1);

    gemm_nt<<<gp, blk, 0, stream>>>(x, wq, nullptr, Q, D_MODEL, D_MODEL, 0, 0, 0);
    gemm_nt<<<gp, blk, 0, stream>>>(x, wk, nullptr, K, D_MODEL, D_MODEL, 0, 0, 0);
    gemm_nt<<<gp, blk, 0, stream>>>(x, wv, nullptr, V, D_MODEL, D_MODEL, 0, 0, 0);
    gemm_nt<<<gp, blk, 0, stream>>>(x, ep_w, ep_b, EF, D_MODEL, D_MODEL, 0, 0, 0);

    ln_rows<<<dim3(M), blk, 0, stream>>>(EF, nullptr, en_g, en_b, EF);

    dim3 ge(L_SEQ / 128, L_SEQ / 128, BATCH);
    gemm_nt<<<ge, blk, 0, stream>>>(EF, EF, nullptr, EB, L_SEQ, D_MODEL,
                                    (long long)L_SEQ * D_MODEL,
                                    (long long)L_SEQ * D_MODEL,
                                    (long long)L_SEQ * L_SEQ);

    cvt_bf16<<<dim3((unsigned)(MD / 1024), 2), blk, 0, stream>>>(Q, K, Qh, Kh);
    transpose_v<<<dim3(L_SEQ / 64, NUM_HEADS, BATCH), blk, 0, stream>>>(V, Vt);

    attn_mfma<<<dim3(L_SEQ / 64, NUM_HEADS, BATCH), blk, 0, stream>>>(Qh, Kh, Vt, EB, attn_out, CTX);

    gemm_nt<<<gp, blk, 0, stream>>>(CTX, wo_w, wo_b, OUT, D_MODEL, D_MODEL, 0, 0, 0);

    ln_rows<<<dim3(M), blk, 0, stream>>>(OUT, x, ln_g, ln_b, out_final);
}

// Round 3
// 923.921 us; speedup vs baseline: 9.4038x; 1.9181x over previous
//
#include <hip/hip_runtime.h>
#include <math.h>

#define D_MODEL 1024
#define NUM_HEADS 16
#define DK 64
#define L_SEQ 2048
#define BATCH 2
#define LN_EPS 1e-5f
#define ENERGY_SCALE 0.1f

typedef __attribute__((ext_vector_type(8))) short short8;
typedef __attribute__((ext_vector_type(4))) float f32x4;
typedef unsigned short ushort_t;

__device__ __forceinline__ float waveReduceSum(float v) {
#pragma unroll
    for (int off = 32; off > 0; off >>= 1) v += __shfl_xor(v, off, 64);
    return v;
}

__device__ __forceinline__ unsigned short f2bf(float f) {
    unsigned int u = __float_as_uint(f);
    u += 0x7fff + ((u >> 16) & 1);          // round-to-nearest-even
    return (unsigned short)(u >> 16);
}

// ---------------- fp32 -> bf16 convert, 6 matrices in one launch ----------------
__global__ __launch_bounds__(256) void cvt6(
    const float* s0, const float* s1, const float* s2,
    const float* s3, const float* s4, const float* s5,
    unsigned short* d0, unsigned short* d1, unsigned short* d2,
    unsigned short* d3, unsigned short* d4, unsigned short* d5,
    long long n0, long long n1, long long n2, long long n3, long long n4, long long n5)
{
    const float* s; unsigned short* d; long long n;
    switch (blockIdx.y) {
        case 0: s = s0; d = d0; n = n0; break;
        case 1: s = s1; d = d1; n = n1; break;
        case 2: s = s2; d = d2; n = n2; break;
        case 3: s = s3; d = d3; n = n3; break;
        case 4: s = s4; d = d4; n = n4; break;
        default: s = s5; d = d5; n = n5; break;
    }
    long long i = ((long long)blockIdx.x * 256 + threadIdx.x) * 4;
    if (i >= n) return;
    float4 v = *(const float4*)(s + i);
    ushort4 o;
    o.x = f2bf(v.x); o.y = f2bf(v.y); o.z = f2bf(v.z); o.w = f2bf(v.w);
    *(ushort4*)(d + i) = o;
}

// ---------------- bf16 MFMA GEMM: C[M,N] = A[M,K] * B[N,K]^T (+bias) ----------------
// 128x128 tile, BK=64, 4 waves (2x2), each wave 64x64 (4x4 MFMA 16x16x32).
__global__ __launch_bounds__(256) void gemm_bf16(
    const unsigned short* __restrict__ A, const unsigned short* __restrict__ B,
    const float* __restrict__ bias, float* __restrict__ Cf, unsigned short* __restrict__ Ch,
    int N, int K, long long sA, long long sB, long long sC)
{
    A += (long long)blockIdx.z * sA;
    B += (long long)blockIdx.z * sB;
    __shared__ unsigned short As[128 * 72];
    __shared__ unsigned short Bs[128 * 72];
    const int tid = threadIdx.x;
    const int lane = tid & 63, w = tid >> 6;
    const int quad = lane >> 4, col = lane & 15;
    const int wm = w & 1, wn = w >> 1;
    const int row0 = blockIdx.y * 128, col0 = blockIdx.x * 128;

    f32x4 acc[4][4];
#pragma unroll
    for (int mt = 0; mt < 4; mt++)
#pragma unroll
        for (int nt = 0; nt < 4; nt++) acc[mt][nt] = (f32x4){0.f, 0.f, 0.f, 0.f};

    for (int k0 = 0; k0 < K; k0 += 64) {
        __syncthreads();
#pragma unroll
        for (int p = 0; p < 4; p++) {
            int u = tid + p * 256;
            int r = u >> 3;
            int c = (u & 7) * 8;
            *(uint4*)(As + r * 72 + c) = *(const uint4*)(A + (long long)(row0 + r) * K + k0 + c);
            *(uint4*)(Bs + r * 72 + c) = *(const uint4*)(B + (long long)(col0 + r) * K + k0 + c);
        }
        __syncthreads();
#pragma unroll
        for (int kc = 0; kc < 2; kc++) {
            short8 af[4], bfr[4];
#pragma unroll
            for (int mt = 0; mt < 4; mt++)
                af[mt] = *(const short8*)(As + (wm * 64 + mt * 16 + col) * 72 + quad * 8 + kc * 32);
#pragma unroll
            for (int nt = 0; nt < 4; nt++)
                bfr[nt] = *(const short8*)(Bs + (wn * 64 + nt * 16 + col) * 72 + quad * 8 + kc * 32);
#pragma unroll
            for (int mt = 0; mt < 4; mt++)
#pragma unroll
                for (int nt = 0; nt < 4; nt++)
                    acc[mt][nt] = __builtin_amdgcn_mfma_f32_16x16x32_bf16(af[mt], bfr[nt], acc[mt][nt], 0, 0, 0);
        }
    }

#pragma unroll
    for (int mt = 0; mt < 4; mt++)
#pragma unroll
        for (int nt = 0; nt < 4; nt++)
#pragma unroll
            for (int reg = 0; reg < 4; reg++) {
                long long row = row0 + wm * 64 + mt * 16 + quad * 4 + reg;
                int c = col0 + wn * 64 + nt * 16 + col;
                float v = acc[mt][nt][reg];
                if (bias) v += bias[c];
                if (Cf) Cf[blockIdx.z * sC + row * N + c] = v;
                else    Ch[blockIdx.z * sC + row * N + c] = f2bf(v);
            }
}

// ---------------- fused projections: z=0..3 -> Qh, Kh, Vf (bf16), EP (fp32+bias) ----------------
__global__ __launch_bounds__(256) void proj_gemm(
    const unsigned short* __restrict__ Xh,
    const unsigned short* __restrict__ wqh, const unsigned short* __restrict__ wkh,
    const unsigned short* __restrict__ wvh, const unsigned short* __restrict__ eph,
    const float* __restrict__ ep_b,
    unsigned short* __restrict__ Qh, unsigned short* __restrict__ Kh,
    unsigned short* __restrict__ Vf, float* __restrict__ EP)
{
    const unsigned short* B;
    switch (blockIdx.z) {
        case 0: B = wqh; break;
        case 1: B = wkh; break;
        case 2: B = wvh; break;
        default: B = eph; break;
    }
    __shared__ unsigned short As[128 * 72];
    __shared__ unsigned short Bs[128 * 72];
    const int tid = threadIdx.x;
    const int lane = tid & 63, w = tid >> 6;
    const int quad = lane >> 4, col = lane & 15;
    const int wm = w & 1, wn = w >> 1;
    const int row0 = blockIdx.y * 128, col0 = blockIdx.x * 128;
    const int K = D_MODEL, N = D_MODEL;

    f32x4 acc[4][4];
#pragma unroll
    for (int mt = 0; mt < 4; mt++)
#pragma unroll
        for (int nt = 0; nt < 4; nt++) acc[mt][nt] = (f32x4){0.f, 0.f, 0.f, 0.f};

    for (int k0 = 0; k0 < K; k0 += 64) {
        __syncthreads();
#pragma unroll
        for (int p = 0; p < 4; p++) {
            int u = tid + p * 256;
            int r = u >> 3;
            int c = (u & 7) * 8;
            *(uint4*)(As + r * 72 + c) = *(const uint4*)(Xh + (long long)(row0 + r) * K + k0 + c);
            *(uint4*)(Bs + r * 72 + c) = *(const uint4*)(B + (long long)(col0 + r) * K + k0 + c);
        }
        __syncthreads();
#pragma unroll
        for (int kc = 0; kc < 2; kc++) {
            short8 af[4], bfr[4];
#pragma unroll
            for (int mt = 0; mt < 4; mt++)
                af[mt] = *(const short8*)(As + (wm * 64 + mt * 16 + col) * 72 + quad * 8 + kc * 32);
#pragma unroll
            for (int nt = 0; nt < 4; nt++)
                bfr[nt] = *(const short8*)(Bs + (wn * 64 + nt * 16 + col) * 72 + quad * 8 + kc * 32);
#pragma unroll
            for (int mt = 0; mt < 4; mt++)
#pragma unroll
                for (int nt = 0; nt < 4; nt++)
                    acc[mt][nt] = __builtin_amdgcn_mfma_f32_16x16x32_bf16(af[mt], bfr[nt], acc[mt][nt], 0, 0, 0);
        }
    }

    unsigned short* Hout = (blockIdx.z == 0) ? Qh : (blockIdx.z == 1) ? Kh : Vf;
#pragma unroll
    for (int mt = 0; mt < 4; mt++)
#pragma unroll
        for (int nt = 0; nt < 4; nt++)
#pragma unroll
            for (int reg = 0; reg < 4; reg++) {
                long long row = row0 + wm * 64 + mt * 16 + quad * 4 + reg;
                int c = col0 + wn * 64 + nt * 16 + col;
                float v = acc[mt][nt][reg];
                if (blockIdx.z == 3) EP[row * N + c] = v + ep_b[c];
                else                 Hout[row * N + c] = f2bf(v);
            }
}

// ---------------- LayerNorm rows; fp32 out (outf) or bf16 out (outh) ----------------
__global__ __launch_bounds__(256) void ln_rows(
    const float* __restrict__ in, const float* __restrict__ res,
    const float* __restrict__ g, const float* __restrict__ bta,
    float* __restrict__ outf, unsigned short* __restrict__ outh)
{
    const long long row = blockIdx.x;
    const float* ip = in + row * D_MODEL;
    const float* rp = res ? res + row * D_MODEL : nullptr;
    const int tid = threadIdx.x;
    float vals[4];
    float s = 0.f, ss = 0.f;
#pragma unroll
    for (int j = 0; j < 4; j++) {
        int idx = tid + j * 256;
        float v = ip[idx];
        if (rp) v += rp[idx];
        vals[j] = v; s += v; ss += v * v;
    }
    __shared__ float sred[4], ssred[4];
    s = waveReduceSum(s); ss = waveReduceSum(ss);
    int wave = tid >> 6, lane = tid & 63;
    if (lane == 0) { sred[wave] = s; ssred[wave] = ss; }
    __syncthreads();
    float ts = sred[0] + sred[1] + sred[2] + sred[3];
    float tss = ssred[0] + ssred[1] + ssred[2] + ssred[3];
    float mu = ts * (1.f / D_MODEL);
    float var = tss * (1.f / D_MODEL) - mu * mu;
    float rs = rsqrtf(var + LN_EPS);
#pragma unroll
    for (int j = 0; j < 4; j++) {
        int idx = tid + j * 256;
        float o = (vals[j] - mu) * rs * g[idx] + bta[idx];
        if (outf) outf[row * D_MODEL + idx] = o;
        else      outh[row * D_MODEL + idx] = f2bf(o);
    }
}

// ---------------- V transpose: Vf[B,L,D] bf16 -> Vt[B,H,DK,L] bf16 ----------------
__global__ __launch_bounds__(256) void transpose_v(
    const unsigned short* __restrict__ V, unsigned short* __restrict__ Vt)
{
    const int m0 = blockIdx.x * 64, h = blockIdx.y, b = blockIdx.z;
    __shared__ unsigned int t[64][65];
    const int tid = threadIdx.x;
    {
        int r = tid >> 4, c4 = (tid & 15) * 4;
#pragma unroll
        for (int i = 0; i < 4; i++) {
            int row = r + i * 16;
            ushort4 v = *(const ushort4*)(V + ((long long)b * L_SEQ + m0 + row) * D_MODEL + h * DK + c4);
            t[row][c4] = v.x; t[row][c4 + 1] = v.y; t[row][c4 + 2] = v.z; t[row][c4 + 3] = v.w;
        }
    }
    __syncthreads();
    const int lane = tid & 63, wv = tid >> 6;
#pragma unroll
    for (int i = 0; i < 16; i++) {
        int d = wv * 16 + i;
        Vt[(((long long)(b * NUM_HEADS + h)) * DK + d) * L_SEQ + m0 + lane] = (unsigned short)t[lane][d];
    }
}

// ---------------- MFMA attention (CTX out as bf16, EB prefetched) ----------------
__global__ __launch_bounds__(256) void attn_mfma(
    const unsigned short* __restrict__ Qh, const unsigned short* __restrict__ Kh,
    const unsigned short* __restrict__ Vt, const float* __restrict__ EB,
    float* __restrict__ attn_out, unsigned short* __restrict__ CTXh)
{
    __shared__ unsigned short Qs[64 * 72];
    __shared__ unsigned short Ks[64 * 72];
    __shared__ unsigned short Vts[64 * 72];
    __shared__ unsigned short Ps[4 * 16 * 72];

    const int tid = threadIdx.x;
    const int lane = tid & 63, w = tid >> 6;
    const int quad = lane >> 4, col = lane & 15;
    const int l0 = blockIdx.x * 64;
    const int h = blockIdx.y, b = blockIdx.z;

    {
        const unsigned short* g = Qh + ((long long)b * L_SEQ + l0) * D_MODEL + h * DK;
        int r = tid >> 2, c0 = (tid & 3) * 16;
#pragma unroll
        for (int i = 0; i < 2; i++) {
            int c = c0 + i * 8;
            *(uint4*)(Qs + r * 72 + c) = *(const uint4*)(g + (long long)r * D_MODEL + c);
        }
    }
    __syncthreads();

    short8 aq[2];
    {
        int arow = w * 16 + col;
#pragma unroll
        for (int kc = 0; kc < 2; kc++)
            aq[kc] = *(const short8*)(Qs + arow * 72 + quad * 8 + kc * 32);
    }

    const float* ebp = EB + ((long long)b * L_SEQ + l0 + w * 16 + quad * 4) * L_SEQ + col;
    const unsigned short* kbase = Kh + ((long long)b * L_SEQ) * D_MODEL + h * DK;
    const unsigned short* vbase = Vt + ((long long)(b * NUM_HEADS + h)) * DK * L_SEQ;

    float rowM[4] = {-1e30f, -1e30f, -1e30f, -1e30f};
    float rowS[4] = {0.f, 0.f, 0.f, 0.f};

    // ================= sweep 1: row max & sum =================
    for (int m0 = 0; m0 < L_SEQ; m0 += 64) {
        __syncthreads();
        float ebv[4][4];
        {
            int r = tid >> 2, c0 = (tid & 3) * 16;
#pragma unroll
            for (int i = 0; i < 2; i++) {
                int c = c0 + i * 8;
                *(uint4*)(Ks + r * 72 + c) = *(const uint4*)(kbase + (long long)(m0 + r) * D_MODEL + c);
            }
#pragma unroll
            for (int nt = 0; nt < 4; nt++)
#pragma unroll
                for (int reg = 0; reg < 4; reg++)
                    ebv[nt][reg] = ebp[(long long)reg * L_SEQ + m0 + nt * 16];
        }
        __syncthreads();

        f32x4 acc[4];
#pragma unroll
        for (int nt = 0; nt < 4; nt++) acc[nt] = (f32x4){0.f, 0.f, 0.f, 0.f};
#pragma unroll
        for (int nt = 0; nt < 4; nt++)
#pragma unroll
            for (int kc = 0; kc < 2; kc++) {
                short8 bk = *(const short8*)(Ks + (nt * 16 + col) * 72 + quad * 8 + kc * 32);
                acc[nt] = __builtin_amdgcn_mfma_f32_16x16x32_bf16(aq[kc], bk, acc[nt], 0, 0, 0);
            }

        float sv[4][4];
#pragma unroll
        for (int nt = 0; nt < 4; nt++)
#pragma unroll
            for (int reg = 0; reg < 4; reg++)
                sv[nt][reg] = acc[nt][reg] * 0.125f + ENERGY_SCALE * ebv[nt][reg];

#pragma unroll
        for (int reg = 0; reg < 4; reg++) {
            float tm = fmaxf(fmaxf(sv[0][reg], sv[1][reg]), fmaxf(sv[2][reg], sv[3][reg]));
#pragma unroll
            for (int off = 8; off > 0; off >>= 1) tm = fmaxf(tm, __shfl_xor(tm, off, 64));
            float nm = fmaxf(rowM[reg], tm);
            float t = __expf(sv[0][reg] - nm) + __expf(sv[1][reg] - nm) +
                      __expf(sv[2][reg] - nm) + __expf(sv[3][reg] - nm);
#pragma unroll
            for (int off = 8; off > 0; off >>= 1) t += __shfl_xor(t, off, 64);
            rowS[reg] = rowS[reg] * __expf(rowM[reg] - nm) + t;
            rowM[reg] = nm;
        }
    }

    float invS[4];
#pragma unroll
    for (int reg = 0; reg < 4; reg++) invS[reg] = 1.f / rowS[reg];

    // ================= sweep 2: write attn, ctx = P V =================
    f32x4 ctx[4];
#pragma unroll
    for (int nt = 0; nt < 4; nt++) ctx[nt] = (f32x4){0.f, 0.f, 0.f, 0.f};

    unsigned short* Psw = Ps + w * 16 * 72;
    float* aob = attn_out + (((long long)(b * NUM_HEADS + h)) * L_SEQ + l0 + w * 16 + quad * 4) * L_SEQ + col;

    for (int m0 = 0; m0 < L_SEQ; m0 += 64) {
        __syncthreads();
        float ebv[4][4];
        {
            int r = tid >> 2, c0 = (tid & 3) * 16;
#pragma unroll
            for (int i = 0; i < 2; i++) {
                int c = c0 + i * 8;
                *(uint4*)(Ks + r * 72 + c) = *(const uint4*)(kbase + (long long)(m0 + r) * D_MODEL + c);
                *(uint4*)(Vts + r * 72 + c) = *(const uint4*)(vbase + (long long)r * L_SEQ + m0 + c);
            }
#pragma unroll
            for (int nt = 0; nt < 4; nt++)
#pragma unroll
                for (int reg = 0; reg < 4; reg++)
                    ebv[nt][reg] = ebp[(long long)reg * L_SEQ + m0 + nt * 16];
        }
        __syncthreads();

        f32x4 acc[4];
#pragma unroll
        for (int nt = 0; nt < 4; nt++) acc[nt] = (f32x4){0.f, 0.f, 0.f, 0.f};
#pragma unroll
        for (int nt = 0; nt < 4; nt++)
#pragma unroll
            for (int kc = 0; kc < 2; kc++) {
                short8 bk = *(const short8*)(Ks + (nt * 16 + col) * 72 + quad * 8 + kc * 32);
                acc[nt] = __builtin_amdgcn_mfma_f32_16x16x32_bf16(aq[kc], bk, acc[nt], 0, 0, 0);
            }

#pragma unroll
        for (int nt = 0; nt < 4; nt++)
#pragma unroll
            for (int reg = 0; reg < 4; reg++) {
                float s = acc[nt][reg] * 0.125f + ENERGY_SCALE * ebv[nt][reg];
                float p = __expf(s - rowM[reg]) * invS[reg];
                aob[(long long)reg * L_SEQ + m0 + nt * 16] = p;
                Psw[(quad * 4 + reg) * 72 + nt * 16 + col] = f2bf(p);
            }

        short8 ap[2];
#pragma unroll
        for (int kc = 0; kc < 2; kc++)
            ap[kc] = *(const short8*)(Psw + col * 72 + quad * 8 + kc * 32);
#pragma unroll
        for (int nt = 0; nt < 4; nt++)
#pragma unroll
            for (int kc = 0; kc < 2; kc++) {
                short8 bv = *(const short8*)(Vts + (nt * 16 + col) * 72 + quad * 8 + kc * 32);
                ctx[nt] = __builtin_amdgcn_mfma_f32_16x16x32_bf16(ap[kc], bv, ctx[nt], 0, 0, 0);
            }
    }

#pragma unroll
    for (int nt = 0; nt < 4; nt++)
#pragma unroll
        for (int reg = 0; reg < 4; reg++)
            CTXh[((long long)b * L_SEQ + l0 + w * 16 + quad * 4 + reg) * D_MODEL + h * DK + nt * 16 + col] =
                f2bf(ctx[nt][reg]);
}

extern "C" void kernel_launch(void* const* d_in, const int* in_sizes, int n_in,
                              void* d_out, int out_size, void* d_ws, size_t ws_size,
                              hipStream_t stream) {
    const float* x    = (const float*)d_in[0];
    const float* wq   = (const float*)d_in[1];
    const float* wk   = (const float*)d_in[2];
    const float* wv   = (const float*)d_in[3];
    const float* wo_w = (const float*)d_in[4];
    const float* wo_b = (const float*)d_in[5];
    const float* ep_w = (const float*)d_in[6];
    const float* ep_b = (const float*)d_in[7];
    const float* en_g = (const float*)d_in[8];
    const float* en_b = (const float*)d_in[9];
    const float* ln_g = (const float*)d_in[10];
    const float* ln_b = (const float*)d_in[11];

    float* out_final = (float*)d_out;
    float* attn_out  = out_final + (long long)BATCH * L_SEQ * D_MODEL;

    const long long MD = (long long)BATCH * L_SEQ * D_MODEL;   // 4,194,304
    const long long WN = (long long)D_MODEL * D_MODEL;         // 1,048,576

    float* EB = (float*)d_ws;                                  // [B,L,L] fp32
    float* EP = EB + (long long)BATCH * L_SEQ * L_SEQ;         // MD fp32 (also OUT)
    unsigned short* Xh   = (unsigned short*)(EP + MD);
    unsigned short* Qh   = Xh + MD;
    unsigned short* Kh   = Qh + MD;
    unsigned short* Vf   = Kh + MD;
    unsigned short* Vt   = Vf + MD;
    unsigned short* EFh  = Vt + MD;
    unsigned short* CTXh = EFh + MD;
    unsigned short* wqh  = CTXh + MD;
    unsigned short* wkh  = wqh + WN;
    unsigned short* wvh  = wkh + WN;
    unsigned short* eph  = wvh + WN;
    unsigned short* woh  = eph + WN;
    float* OUT = EP;                                           // EP dead after ln

    const int M = BATCH * L_SEQ;                               // 4096
    dim3 blk(256);

    cvt6<<<dim3((unsigned)(MD / 1024), 6), blk, 0, stream>>>(
        x, wq, wk, wv, ep_w, wo_w, Xh, wqh, wkh, wvh, eph, woh,
        MD, WN, WN, WN, WN, WN);

    proj_gemm<<<dim3(D_MODEL / 128, M / 128, 4), blk, 0, stream>>>(
        Xh, wqh, wkh, wvh, eph, ep_b, Qh, Kh, Vf, EP);

    ln_rows<<<dim3(M), blk, 0, stream>>>(EP, nullptr, en_g, en_b, nullptr, EFh);

    gemm_bf16<<<dim3(L_SEQ / 128, L_SEQ / 128, BATCH), blk, 0, stream>>>(
        EFh, EFh, nullptr, EB, nullptr, L_SEQ, D_MODEL,
        (long long)L_SEQ * D_MODEL, (long long)L_SEQ * D_MODEL,
        (long long)L_SEQ * L_SEQ);

    transpose_v<<<dim3(L_SEQ / 64, NUM_HEADS, BATCH), blk, 0, stream>>>(Vf, Vt);

    attn_mfma<<<dim3(L_SEQ / 64, NUM_HEADS, BATCH), blk, 0, stream>>>(
        Qh, Kh, Vt, EB, attn_out, CTXh);

    gemm_bf16<<<dim3(D_MODEL / 128, M / 128, 1), blk, 0, stream>>>(
        CTXh, woh, wo_b, OUT, nullptr, D_MODEL, D_MODEL, 0, 0, 0);

    ln_rows<<<dim3(M), blk, 0, stream>>>(OUT, x, ln_g, ln_b, out_final, nullptr);
}